// Round 4
// baseline (45.456 us; speedup 1.0000x reference)
//
#include <hip/hip_runtime.h>
#include <math.h>

#define EPSF 1e-9f
#define FOUR_PI 12.566370614359172f
#define YIM (-(FOUR_PI * 1e-9f))   // constant imag part of k^2 argument

__device__ __forceinline__ float frcp(float x) { return __builtin_amdgcn_rcpf(x); }
__device__ __forceinline__ float frsq(float x) { return __builtin_amdgcn_rsqf(x); }
__device__ __forceinline__ float fsq(float x)  { return __builtin_amdgcn_sqrtf(x); }

// 2^x (native v_exp_f32); callers pre-fold log2(e) into constants.
#if __has_builtin(__builtin_amdgcn_exp2f)
__device__ __forceinline__ float fexp2(float x) { return __builtin_amdgcn_exp2f(x); }
#else
__device__ __forceinline__ float fexp2(float x) { return __expf(x * 0.6931471805599453f); }
#endif

// sin/cos with input in REVOLUTIONS (already range-reduced to [0,1)).
#if __has_builtin(__builtin_amdgcn_sinf) && __has_builtin(__builtin_amdgcn_cosf)
__device__ __forceinline__ float fsin_rev(float x) { return __builtin_amdgcn_sinf(x); }
__device__ __forceinline__ float fcos_rev(float x) { return __builtin_amdgcn_cosf(x); }
#else
__device__ __forceinline__ float fsin_rev(float x) { return __sinf(x * 6.283185307179586f); }
__device__ __forceinline__ float fcos_rev(float x) { return __cosf(x * 6.283185307179586f); }
#endif

__device__ __forceinline__ float redrev(float x) { return x - floorf(x); }  // to [0,1)

// principal sqrt of (x + i*YIM), YIM < 0 constant; cancellation-free.
__device__ __forceinline__ void csqrt_negim(float x, float& u, float& v) {
    float r   = fsq(fmaf(x, x, YIM * YIM));
    float h   = 0.5f * (r + fabsf(x));
    float irs = frsq(h);
    float w   = h * irs;            // sqrt(h), large component > 0
    float o   = (0.5f * YIM) * irs; // small component <= 0
    if (x >= 0.0f) { u = w;  v = o;  }
    else           { u = -o; v = -w; }
}

// Precompute per-layer wave-uniform constants into ws:
//   xp[b][j] = 4pi*1e-6*(sld[j]-sld[0]), j=0..L
//   pk[b][j] = { 2t*log2e, 2t/(2pi), -2s^2*log2e, -2s^2/(2pi) }, j=0..L-1
__global__ void prep_kernel(const float* __restrict__ thick,
                            const float* __restrict__ rough,
                            const float* __restrict__ sld,
                            float* __restrict__ xp,
                            float4* __restrict__ pk, int L)
{
    const int b = blockIdx.x, tx = threadIdx.x;
    const float LOG2E  = 1.4426950408889634f;
    const float INV2PI = 0.15915494309189535f;
    const float s0 = sld[(size_t)b * (L + 1)];
    for (int j = tx; j < L; j += blockDim.x) {
        float t  = thick[(size_t)b * L + j];
        float sg = rough[(size_t)b * L + j];
        float s2 = sg * sg;
        pk[(size_t)b * L + j] = make_float4(2.0f * t * LOG2E, 2.0f * t * INV2PI,
                                            -2.0f * s2 * LOG2E, -2.0f * s2 * INV2PI);
        xp[(size_t)b * (L + 1) + j] = (FOUR_PI * 1e-6f) * (sld[(size_t)b * (L + 1) + j] - s0);
    }
    if (tx == 0)
        xp[(size_t)b * (L + 1) + L] = (FOUR_PI * 1e-6f) * (sld[(size_t)b * (L + 1) + L] - s0);
}

__global__ __launch_bounds__(256) void abeles_kernel(
    const float*  __restrict__ qarr,  // B*Q
    const float*  __restrict__ xp,    // B*(L+1), wave-uniform reads
    const float4* __restrict__ pk,    // B*L, wave-uniform reads
    float* __restrict__ out, int Q, int L)
{
    const int b  = blockIdx.y;
    const int iq = blockIdx.x * blockDim.x + threadIdx.x;
    const float*  xpb = xp + (size_t)b * (L + 1);
    const float4* pkb = pk + (size_t)b * L;

    float qh = (iq < Q) ? 0.5f * qarr[(size_t)b * Q + iq] : 0.05f;
    float q2 = qh * qh;

    // substrate k; R = N/D with N=0, D=1
    float u2, v2;
    csqrt_negim(q2 - xpb[L], u2, v2);
    float Nr = 0.0f, Ni = 0.0f, Dr = 1.0f, Di = 0.0f;

    #pragma unroll 8
    for (int j = L - 1; j >= 0; --j) {
        const float4 P = pkb[j];          // t2e, t2r, m2e, m2r (uniform -> SGPR)
        float u1, v1;
        csqrt_negim(q2 - xpb[j], u1, v1);

        // fresnel numerator/denominator (no divide)
        float nr = u1 - u2, ni = v1 - v2;
        float er = u1 + u2 + EPSF, ei = v1 + v2;

        // roughness factor exp(-2 s^2 k1 k2) applied to numerator
        float kkr = u1 * u2 - v1 * v2;
        float kki = u1 * v2 + v1 * u2;
        float ew  = fexp2(P.z * kkr);
        float ar  = redrev(P.w * kki);
        float sw = fsin_rev(ar), cw = fcos_rev(ar);
        float fr = ew * cw, fi = ew * sw;
        float t0 = nr * fr - ni * fi;
        ni = fmaf(nr, fi, ni * fr);
        nr = t0;

        // Mobius update: N' = p*(n*D + d*N), D' = d*D + n*N
        float tnr = fmaf(nr, Dr, fmaf(-ni, Di, fmaf(er, Nr, -ei * Ni)));
        float tni = fmaf(nr, Di, fmaf( ni, Dr, fmaf(er, Ni,  ei * Nr)));
        float tdr = fmaf(er, Dr, fmaf(-ei, Di, fmaf(nr, Nr, -ni * Ni)));
        float tdi = fmaf(er, Di, fmaf( ei, Dr, fmaf(nr, Ni,  ni * Nr)));

        // phase p = e^{-2 i t k1}: |p| = 2^(t2e*v1), angle = -(t2r*u1) rev
        float pm = fexp2(P.x * v1);
        float pa = redrev(P.y * u1);
        float sp = fsin_rev(pa), cp = fcos_rev(pa);
        float pr = pm * cp, pi = -pm * sp;

        Nr = tnr * pr - tni * pi;
        Ni = fmaf(tnr, pi, tni * pr);
        Dr = tdr; Di = tdi;
        u2 = u1; v2 = v1;

        // exponent renorm every 8 layers (ratio-preserving power of 2)
        if ((j & 7) == 0) {
            float m = fabsf(Dr) + fabsf(Di);
            int eb = (__float_as_int(m) >> 23) & 0xff;
            float s = __int_as_float((254 - eb) << 23);
            Nr *= s; Ni *= s; Dr *= s; Di *= s;
        }
    }

    float inv = frcp(fmaf(Dr, Dr, Di * Di));
    if (iq < Q) out[(size_t)b * Q + iq] = fmaf(Nr, Nr, Ni * Ni) * inv;
}

extern "C" void kernel_launch(void* const* d_in, const int* in_sizes, int n_in,
                              void* d_out, int out_size, void* d_ws, size_t ws_size,
                              hipStream_t stream) {
    const float* q     = (const float*)d_in[0];
    const float* thick = (const float*)d_in[1];
    const float* rough = (const float*)d_in[2];
    const float* sld   = (const float*)d_in[3];
    float* out = (float*)d_out;

    int B = in_sizes[3] - in_sizes[1];   // B*(L+1) - B*L
    int L = in_sizes[1] / B;
    int Q = in_sizes[0] / B;

    float* xp = (float*)d_ws;
    size_t xpBytes = (((size_t)B * (L + 1) * sizeof(float)) + 255) & ~(size_t)255;
    float4* pk = (float4*)((char*)d_ws + xpBytes);

    prep_kernel<<<dim3(B), dim3(64), 0, stream>>>(thick, rough, sld, xp, pk, L);

    dim3 block(256);
    dim3 grid((Q + 255) / 256, B);
    abeles_kernel<<<grid, block, 0, stream>>>(q, xp, pk, out, Q, L);
}

// Round 5
// 36.457 us; speedup vs baseline: 1.2468x; 1.2468x over previous
//
#include <hip/hip_runtime.h>
#include <math.h>

#define EPSF 1e-9f
#define FOUR_PI 12.566370614359172f
#define YIM (-(FOUR_PI * 1e-9f))   // constant imag part of k^2 argument
#define LOG2E  1.4426950408889634f
#define INV2PI 0.15915494309189535f

__device__ __forceinline__ float frcp(float x) { return __builtin_amdgcn_rcpf(x); }
__device__ __forceinline__ float frsq(float x) { return __builtin_amdgcn_rsqf(x); }
__device__ __forceinline__ float fsq(float x)  { return __builtin_amdgcn_sqrtf(x); }

#if __has_builtin(__builtin_amdgcn_exp2f)
__device__ __forceinline__ float fexp2(float x) { return __builtin_amdgcn_exp2f(x); }
#else
__device__ __forceinline__ float fexp2(float x) { return exp2f(x); }
#endif
#if __has_builtin(__builtin_amdgcn_sinf) && __has_builtin(__builtin_amdgcn_cosf)
__device__ __forceinline__ float fsin_rev(float x) { return __builtin_amdgcn_sinf(x); }
__device__ __forceinline__ float fcos_rev(float x) { return __builtin_amdgcn_cosf(x); }
#else
__device__ __forceinline__ float fsin_rev(float x) { return __sinf(x * 6.283185307179586f); }
__device__ __forceinline__ float fcos_rev(float x) { return __cosf(x * 6.283185307179586f); }
#endif
#if __has_builtin(__builtin_amdgcn_fractf)
__device__ __forceinline__ float ffract(float x) { return __builtin_amdgcn_fractf(x); }
#else
__device__ __forceinline__ float ffract(float x) { return x - floorf(x); }
#endif

// principal sqrt of (x + i*YIM), YIM < 0 constant; cancellation-free.
__device__ __forceinline__ void csqrt_negim(float x, float& u, float& v) {
    float r   = fsq(fmaf(x, x, YIM * YIM));
    float h   = fmaf(0.5f, r, 0.5f * fabsf(x));
    float irs = frsq(h);
    float w   = h * irs;            // sqrt(h), large component > 0
    float o   = (0.5f * YIM) * irs; // small component <= 0
    if (x >= 0.0f) { u = w;  v = o;  }
    else           { u = -o; v = -w; }
}

#define RENORM() do {                                          \
    float m_ = fabsf(Dr) + fabsf(Di);                          \
    int eb_ = (__float_as_int(m_) >> 23) & 0xff;               \
    float s_ = __int_as_float((254 - eb_) << 23);              \
    Nr *= s_; Ni *= s_; Dr *= s_; Di *= s_;                    \
} while (0)

__global__ __launch_bounds__(256, 4) void abeles_kernel(
    const float* __restrict__ qarr,   // B*Q
    const float* __restrict__ thick,  // B*L
    const float* __restrict__ rough,  // B*L
    const float* __restrict__ sld,    // B*(L+1)
    float* __restrict__ out,          // B*Q
    int Q, int L)
{
    const int b  = blockIdx.y;
    const int tx = threadIdx.x;

    __shared__ float s_xp[65];    // 4pi*1e-6*(sld[j]-sld[0])
    __shared__ float s_t2e[64];   // 2t*log2e
    __shared__ float s_t2r[64];   // 2t/(2pi)
    __shared__ float s_m2e[64];   // -2*sigma^2*log2e
    __shared__ float s_m2[64];    // -2*sigma^2   (radians, for Taylor sin/cos)

    {
        float s0 = sld[(size_t)b * (L + 1)];
        for (int i = tx; i < L + 1; i += blockDim.x)
            s_xp[i] = (FOUR_PI * 1e-6f) * (sld[(size_t)b * (L + 1) + i] - s0);
        for (int i = tx; i < L; i += blockDim.x) {
            float t  = thick[(size_t)b * L + i];
            float sg = rough[(size_t)b * L + i];
            float s2 = sg * sg;
            s_t2e[i] = 2.0f * t * LOG2E;
            s_t2r[i] = 2.0f * t * INV2PI;
            s_m2e[i] = -2.0f * s2 * LOG2E;
            s_m2[i]  = -2.0f * s2;
        }
    }
    const int iq = blockIdx.x * blockDim.x + tx;
    float qh = (iq < Q) ? 0.5f * qarr[(size_t)b * Q + iq] : 0.05f;
    float q2 = qh * qh;
    __syncthreads();

    // carried k = substrate (layer L); R = N/D, N=0, D=1
    float cu, cv;
    csqrt_negim(q2 - s_xp[L], cu, cv);
    float Nr = 0.0f, Ni = 0.0f, Dr = 1.0f, Di = 0.0f;

    int j = L;
    while (j >= 8) {
        const int g = j - 8;

        // ---- batch: 8 independent csqrts (pure ILP, pipelines the trans ops)
        float ku[8], kv[8];
        #pragma unroll
        for (int t = 0; t < 8; ++t)
            csqrt_negim(q2 - s_xp[g + t], ku[t], kv[t]);

        // ---- batch: 8 independent ingredient sets (A = n*f, E = e, P = phase)
        float Ar[8], Ai[8], Er[8], Ei[8], Pr[8], Pi[8];
        #pragma unroll
        for (int t = 7; t >= 0; --t) {
            float u1 = ku[t], v1 = kv[t];
            float u2 = (t == 7) ? cu : ku[t + 1];
            float v2 = (t == 7) ? cv : kv[t + 1];

            float nr = u1 - u2, ni = v1 - v2;
            float er = u1 + u2 + EPSF, ei = v1 + v2;

            float kkr = fmaf(u1, u2, -(v1 * v2));
            float kki = fmaf(u1, v2, v1 * u2);
            float ew  = fexp2(s_m2e[g + t] * kkr);
            // roughness angle |a| <= ~0.1 rad: 2nd-order Taylor, no trig
            float a  = s_m2[g + t] * kki;
            float a2 = a * a;
            float cw = fmaf(a2, -0.5f, 1.0f);
            float sw = a * fmaf(a2, -0.16666667f, 1.0f);
            float fr = ew * cw, fi = ew * sw;
            Ar[t] = fmaf(nr, fr, -(ni * fi));
            Ai[t] = fmaf(nr, fi, ni * fr);
            Er[t] = er; Ei[t] = ei;

            float pm = fexp2(s_t2e[g + t] * v1);
            float pa = ffract(s_t2r[g + t] * u1);
            Pr[t] = pm * fcos_rev(pa);
            Pi[t] = -pm * fsin_rev(pa);
        }

        // ---- serial Mobius sweep (short dependency: ~4 fma deep per layer)
        #pragma unroll
        for (int t = 7; t >= 0; --t) {
            float tnr = fmaf(Ar[t], Dr, fmaf(-Ai[t], Di, fmaf(Er[t], Nr, -(Ei[t] * Ni))));
            float tni = fmaf(Ar[t], Di, fmaf( Ai[t], Dr, fmaf(Er[t], Ni,   Ei[t] * Nr)));
            float tdr = fmaf(Er[t], Dr, fmaf(-Ei[t], Di, fmaf(Ar[t], Nr, -(Ai[t] * Ni))));
            float tdi = fmaf(Er[t], Di, fmaf( Ei[t], Dr, fmaf(Ar[t], Ni,   Ai[t] * Nr)));
            Nr = fmaf(tnr, Pr[t], -(tni * Pi[t]));
            Ni = fmaf(tnr, Pi[t],   tni * Pr[t]);
            Dr = tdr; Di = tdi;
            if (t == 4 || t == 0) RENORM();   // worst-case shrink ~1e-5/layer
        }

        cu = ku[0]; cv = kv[0];
        j = g;
    }

    // remainder layers (L % 8), scalar path — not taken for L=64
    while (j > 0) {
        --j;
        float u1, v1;
        csqrt_negim(q2 - s_xp[j], u1, v1);
        float nr = u1 - cu, ni = v1 - cv;
        float er = u1 + cu + EPSF, ei = v1 + cv;
        float kkr = fmaf(u1, cu, -(v1 * cv));
        float kki = fmaf(u1, cv, v1 * cu);
        float ew  = fexp2(s_m2e[j] * kkr);
        float a   = s_m2[j] * kki;
        float a2  = a * a;
        float cw = fmaf(a2, -0.5f, 1.0f);
        float sw = a * fmaf(a2, -0.16666667f, 1.0f);
        float fr = ew * cw, fi = ew * sw;
        float Arv = fmaf(nr, fr, -(ni * fi));
        float Aiv = fmaf(nr, fi, ni * fr);
        float pm = fexp2(s_t2e[j] * v1);
        float pa = ffract(s_t2r[j] * u1);
        float pr = pm * fcos_rev(pa);
        float pi = -pm * fsin_rev(pa);
        float tnr = fmaf(Arv, Dr, fmaf(-Aiv, Di, fmaf(er, Nr, -(ei * Ni))));
        float tni = fmaf(Arv, Di, fmaf( Aiv, Dr, fmaf(er, Ni,   ei * Nr)));
        float tdr = fmaf(er, Dr, fmaf(-ei, Di, fmaf(Arv, Nr, -(Aiv * Ni))));
        float tdi = fmaf(er, Di, fmaf( ei, Dr, fmaf(Arv, Ni,   Aiv * Nr)));
        Nr = fmaf(tnr, pr, -(tni * pi));
        Ni = fmaf(tnr, pi,   tni * pr);
        Dr = tdr; Di = tdi;
        RENORM();
        cu = u1; cv = v1;
    }

    float inv = frcp(fmaf(Dr, Dr, Di * Di));
    if (iq < Q) out[(size_t)b * Q + iq] = fmaf(Nr, Nr, Ni * Ni) * inv;
}

extern "C" void kernel_launch(void* const* d_in, const int* in_sizes, int n_in,
                              void* d_out, int out_size, void* d_ws, size_t ws_size,
                              hipStream_t stream) {
    const float* q     = (const float*)d_in[0];
    const float* thick = (const float*)d_in[1];
    const float* rough = (const float*)d_in[2];
    const float* sld   = (const float*)d_in[3];
    float* out = (float*)d_out;

    int B = in_sizes[3] - in_sizes[1];   // B*(L+1) - B*L
    int L = in_sizes[1] / B;
    int Q = in_sizes[0] / B;

    dim3 block(256);
    dim3 grid((Q + 255) / 256, B);
    abeles_kernel<<<grid, block, 0, stream>>>(q, thick, rough, sld, out, Q, L);
}

// Round 6
// 28.395 us; speedup vs baseline: 1.6008x; 1.2839x over previous
//
#include <hip/hip_runtime.h>
#include <math.h>

typedef float v2f __attribute__((ext_vector_type(2)));

#define EPSF 1e-9f
#define FOUR_PI 12.566370614359172f
#define YIM (-(FOUR_PI * 1e-9f))   // constant imag part of k^2 argument
#define LOG2E  1.4426950408889634f
#define INV2PI 0.15915494309189535f

__device__ __forceinline__ float frcp(float x) { return __builtin_amdgcn_rcpf(x); }
__device__ __forceinline__ float frsq(float x) { return __builtin_amdgcn_rsqf(x); }
__device__ __forceinline__ float fsq(float x)  { return __builtin_amdgcn_sqrtf(x); }

#if __has_builtin(__builtin_amdgcn_exp2f)
__device__ __forceinline__ float fexp2(float x) { return __builtin_amdgcn_exp2f(x); }
#else
__device__ __forceinline__ float fexp2(float x) { return exp2f(x); }
#endif
#if __has_builtin(__builtin_amdgcn_sinf) && __has_builtin(__builtin_amdgcn_cosf)
__device__ __forceinline__ float fsin_rev(float x) { return __builtin_amdgcn_sinf(x); }
__device__ __forceinline__ float fcos_rev(float x) { return __builtin_amdgcn_cosf(x); }
#else
__device__ __forceinline__ float fsin_rev(float x) { return __sinf(x * 6.283185307179586f); }
__device__ __forceinline__ float fcos_rev(float x) { return __cosf(x * 6.283185307179586f); }
#endif
#if __has_builtin(__builtin_amdgcn_fractf)
__device__ __forceinline__ float ffract(float x) { return __builtin_amdgcn_fractf(x); }
#else
__device__ __forceinline__ float ffract(float x) { return x - floorf(x); }
#endif

__device__ __forceinline__ v2f vfma(v2f a, v2f b, v2f c) { return __builtin_elementwise_fma(a, b, c); }
__device__ __forceinline__ v2f vabs(v2f a) { return __builtin_elementwise_abs(a); }

// packed principal sqrt of (x + i*YIM), YIM < 0 constant; cancellation-free.
__device__ __forceinline__ void csqrt2(v2f x, v2f& u, v2f& v) {
    v2f r;
    r.x = fsq(fmaf(x.x, x.x, YIM * YIM));
    r.y = fsq(fmaf(x.y, x.y, YIM * YIM));
    v2f h = 0.5f * (r + vabs(x));
    v2f irs; irs.x = frsq(h.x); irs.y = frsq(h.y);
    v2f w = h * irs;                 // sqrt(h), large component > 0
    v2f o = (0.5f * YIM) * irs;      // small component <= 0
    u.x = (x.x >= 0.0f) ? w.x : -o.x;
    v.x = (x.x >= 0.0f) ? o.x : -w.x;
    u.y = (x.y >= 0.0f) ? w.y : -o.y;
    v.y = (x.y >= 0.0f) ? o.y : -w.y;
}

#define RENORM() do {                                            \
    v2f m_ = vabs(Dr) + vabs(Di);                                \
    int ex_ = (__float_as_int(m_.x) >> 23) & 0xff;               \
    int ey_ = (__float_as_int(m_.y) >> 23) & 0xff;               \
    v2f s_;                                                      \
    s_.x = __int_as_float((254 - ex_) << 23);                    \
    s_.y = __int_as_float((254 - ey_) << 23);                    \
    Nr *= s_; Ni *= s_; Dr *= s_; Di *= s_;                      \
} while (0)

__global__ __launch_bounds__(256, 2) void abeles_kernel(
    const float* __restrict__ qarr,   // B*Q
    const float* __restrict__ thick,  // B*L
    const float* __restrict__ rough,  // B*L
    const float* __restrict__ sld,    // B*(L+1)
    float* __restrict__ out,          // B*Q
    int Q, int L)
{
    const int b  = blockIdx.y;
    const int tx = threadIdx.x;

    __shared__ float  s_xp[65];   // 4pi*1e-6*(sld[j]-sld[0])
    __shared__ float4 s_pk[64];   // { 2t*log2e, 2t/(2pi), -2s^2*log2e, -2s^2 }

    {
        float s0 = sld[(size_t)b * (L + 1)];
        for (int i = tx; i < L + 1; i += blockDim.x)
            s_xp[i] = (FOUR_PI * 1e-6f) * (sld[(size_t)b * (L + 1) + i] - s0);
        for (int i = tx; i < L; i += blockDim.x) {
            float t  = thick[(size_t)b * L + i];
            float sg = rough[(size_t)b * L + i];
            float s2 = sg * sg;
            s_pk[i] = make_float4(2.0f * t * LOG2E, 2.0f * t * INV2PI,
                                  -2.0f * s2 * LOG2E, -2.0f * s2);
        }
    }

    // two q-chains per thread, packed in .x/.y
    const int iq0 = blockIdx.x * (2 * blockDim.x) + tx;
    const int iq1 = iq0 + blockDim.x;
    float qa = (iq0 < Q) ? qarr[(size_t)b * Q + iq0] : 0.1f;
    float qb = (iq1 < Q) ? qarr[(size_t)b * Q + iq1] : 0.1f;
    v2f q2; q2.x = 0.25f * qa * qa; q2.y = 0.25f * qb * qb;
    __syncthreads();

    // carried k = substrate; R = N/D, N=0, D=1
    v2f cu, cv;
    csqrt2(q2 - s_xp[L], cu, cv);
    v2f Nr = (v2f)0.0f, Ni = (v2f)0.0f, Dr = (v2f)1.0f, Di = (v2f)0.0f;

    int j = L;
    while (j >= 8) {
        const int g = j - 8;

        // ---- batch: 8 packed csqrts (16 independent scalar streams)
        v2f ku[8], kv[8];
        #pragma unroll
        for (int t = 0; t < 8; ++t)
            csqrt2(q2 - s_xp[g + t], ku[t], kv[t]);

        // ---- batch: 8 packed ingredient sets
        v2f Ar[8], Ai[8], Er[8], Ei[8], Pr[8], Pi[8];
        #pragma unroll
        for (int t = 7; t >= 0; --t) {
            v2f u1 = ku[t], v1 = kv[t];
            v2f u2 = (t == 7) ? cu : ku[t + 1];
            v2f v2_ = (t == 7) ? cv : kv[t + 1];
            const float4 P = s_pk[g + t];

            v2f nr = u1 - u2, ni = v1 - v2_;
            Er[t] = u1 + u2 + EPSF; Ei[t] = v1 + v2_;

            v2f kkr = vfma(u1, u2, -(v1 * v2_));
            v2f kki = vfma(u1, v2_, v1 * u2);
            v2f ew; ew.x = fexp2(P.z * kkr.x); ew.y = fexp2(P.z * kkr.y);
            // roughness angle |a| <= ~0.1 rad: 2nd-order Taylor, no trig
            v2f a  = P.w * kki;
            v2f a2 = a * a;
            v2f cw = vfma(a2, (v2f)(-0.5f), (v2f)1.0f);
            v2f sw = a * vfma(a2, (v2f)(-0.16666667f), (v2f)1.0f);
            v2f fr = ew * cw, fi = ew * sw;
            Ar[t] = vfma(nr, fr, -(ni * fi));
            Ai[t] = vfma(nr, fi, ni * fr);

            v2f pm; pm.x = fexp2(P.x * v1.x); pm.y = fexp2(P.x * v1.y);
            v2f cp, sp;
            {
                float pax = ffract(P.y * u1.x), pay = ffract(P.y * u1.y);
                cp.x = fcos_rev(pax); sp.x = fsin_rev(pax);
                cp.y = fcos_rev(pay); sp.y = fsin_rev(pay);
            }
            Pr[t] = pm * cp;
            Pi[t] = -pm * sp;
        }

        // ---- serial packed Mobius sweep
        #pragma unroll
        for (int t = 7; t >= 0; --t) {
            v2f tnr = vfma(Ar[t], Dr, vfma(-Ai[t], Di, vfma(Er[t], Nr, -(Ei[t] * Ni))));
            v2f tni = vfma(Ar[t], Di, vfma( Ai[t], Dr, vfma(Er[t], Ni,   Ei[t] * Nr)));
            v2f tdr = vfma(Er[t], Dr, vfma(-Ei[t], Di, vfma(Ar[t], Nr, -(Ai[t] * Ni))));
            v2f tdi = vfma(Er[t], Di, vfma( Ei[t], Dr, vfma(Ar[t], Ni,   Ai[t] * Nr)));
            Nr = vfma(tnr, Pr[t], -(tni * Pi[t]));
            Ni = vfma(tnr, Pi[t],   tni * Pr[t]);
            Dr = tdr; Di = tdi;
            if (t == 4 || t == 0) RENORM();
        }

        cu = ku[0]; cv = kv[0];
        j = g;
    }

    // remainder layers (L % 8) — generic path, not taken for L=64
    while (j > 0) {
        --j;
        v2f u1, v1;
        csqrt2(q2 - s_xp[j], u1, v1);
        const float4 P = s_pk[j];
        v2f nr = u1 - cu, ni = v1 - cv;
        v2f er = u1 + cu + EPSF, ei = v1 + cv;
        v2f kkr = vfma(u1, cu, -(v1 * cv));
        v2f kki = vfma(u1, cv, v1 * cu);
        v2f ew; ew.x = fexp2(P.z * kkr.x); ew.y = fexp2(P.z * kkr.y);
        v2f a = P.w * kki, a2 = a * a;
        v2f cw = vfma(a2, (v2f)(-0.5f), (v2f)1.0f);
        v2f sw = a * vfma(a2, (v2f)(-0.16666667f), (v2f)1.0f);
        v2f fr = ew * cw, fi = ew * sw;
        v2f Arv = vfma(nr, fr, -(ni * fi));
        v2f Aiv = vfma(nr, fi, ni * fr);
        v2f pm; pm.x = fexp2(P.x * v1.x); pm.y = fexp2(P.x * v1.y);
        float pax = ffract(P.y * u1.x), pay = ffract(P.y * u1.y);
        v2f cp, sp;
        cp.x = fcos_rev(pax); sp.x = fsin_rev(pax);
        cp.y = fcos_rev(pay); sp.y = fsin_rev(pay);
        v2f pr = pm * cp, pi = -pm * sp;
        v2f tnr = vfma(Arv, Dr, vfma(-Aiv, Di, vfma(er, Nr, -(ei * Ni))));
        v2f tni = vfma(Arv, Di, vfma( Aiv, Dr, vfma(er, Ni,   ei * Nr)));
        v2f tdr = vfma(er, Dr, vfma(-ei, Di, vfma(Arv, Nr, -(Aiv * Ni))));
        v2f tdi = vfma(er, Di, vfma( ei, Dr, vfma(Arv, Ni,   Aiv * Nr)));
        Nr = vfma(tnr, pr, -(tni * pi));
        Ni = vfma(tnr, pi,   tni * pr);
        Dr = tdr; Di = tdi;
        RENORM();
        cu = u1; cv = v1;
    }

    v2f d2 = vfma(Dr, Dr, Di * Di);
    v2f n2 = vfma(Nr, Nr, Ni * Ni);
    if (iq0 < Q) out[(size_t)b * Q + iq0] = n2.x * frcp(d2.x);
    if (iq1 < Q) out[(size_t)b * Q + iq1] = n2.y * frcp(d2.y);
}

extern "C" void kernel_launch(void* const* d_in, const int* in_sizes, int n_in,
                              void* d_out, int out_size, void* d_ws, size_t ws_size,
                              hipStream_t stream) {
    const float* q     = (const float*)d_in[0];
    const float* thick = (const float*)d_in[1];
    const float* rough = (const float*)d_in[2];
    const float* sld   = (const float*)d_in[3];
    float* out = (float*)d_out;

    int B = in_sizes[3] - in_sizes[1];   // B*(L+1) - B*L
    int L = in_sizes[1] / B;
    int Q = in_sizes[0] / B;

    dim3 block(256);
    dim3 grid((Q + 511) / 512, B);
    abeles_kernel<<<grid, block, 0, stream>>>(q, thick, rough, sld, out, Q, L);
}